// Round 7
// baseline (406.245 us; speedup 1.0000x reference)
//
#include <hip/hip_runtime.h>
#include <math.h>

// GraphCritic: GCNConv (sym-norm + self-loops) -> per-column lower median ->
// tanh MLP -> scalar.
// v7: k_agg = 2 nodes/wave (divergent halves, float4 lanes, width-32 shfl,
//     16 rows in flight/wave) and split into TWO dispatches (visibility: R6's
//     top-5 was all k_agg replays, hiding the 279us tail). k_gemm epilogue:
//     wave-private LDS transpose -> float4-coalesced xw stores.

#define CAP    24576   // candidate capacity per column (expect ~14.3K)
#define CCAP   96      // per-block per-column LDS candidate buffer
#define DSTR   32      // adjacency slots per node
#define OVCAP  4096    // overflow edge capacity (deg>32 spill, expect ~5)
#define BCAP   4608    // edges per 256-node bucket (mean 4092, sd 64: +8 sigma)
#define NBKMAX 400
#define CH     4096    // k_bin chunk size

typedef __attribute__((ext_vector_type(8))) short short8;   // 8 bf16
typedef __attribute__((ext_vector_type(4))) float f32x4;

__device__ __forceinline__ unsigned ordKey(float x) {
    unsigned u = __float_as_uint(x);
    return (u & 0x80000000u) ? ~u : (u | 0x80000000u);
}
__device__ __forceinline__ float keyToFloat(unsigned k) {
    unsigned bits = (k & 0x80000000u) ? (k & 0x7FFFFFFFu) : ~k;
    return __uint_as_float(bits);
}
__device__ __forceinline__ unsigned short f2bf(float f) {   // RNE
    unsigned u = __float_as_uint(f);
    return (unsigned short)((u + 0x7FFFu + ((u >> 16) & 1u)) >> 16);
}

// ---------------- init: zero cursor/below/candCnt/ovCnt; W -> frag layout --
__global__ void k_init(int* __restrict__ cursor, int* __restrict__ below,
                       int* __restrict__ candCnt, int* __restrict__ ovCnt,
                       const float* __restrict__ W, short* __restrict__ Whi,
                       short* __restrict__ Wlo, int nbk) {
    if (blockIdx.x == 1) {
        for (int idx = threadIdx.x; idx < 16384; idx += 256) {
            int j = idx & 7, lane = (idx >> 3) & 63;
            int t = (idx >> 9) & 7, s = idx >> 12;
            int row = t * 16 + (lane & 15);
            int k = s * 32 + (lane >> 4) * 8 + j;
            float w = W[row * 128 + k];
            unsigned short hb = f2bf(w);
            float hf = __uint_as_float((unsigned)hb << 16);
            Whi[idx] = (short)hb;
            Wlo[idx] = (short)f2bf(w - hf);
        }
        return;
    }
    int t = threadIdx.x;
    for (int i = t; i < nbk; i += 256) cursor[i] = 0;
    if (t < 128) { below[t] = 0; candCnt[t] = 0; }
    if (t == 0) ovCnt[0] = 0;
}

// ---------------- bin: chunked LDS binning by 256-node bucket -------------
__global__ __launch_bounds__(256) void k_bin(const int* __restrict__ src,
                                             const int* __restrict__ dst, int E,
                                             int* __restrict__ cursor,
                                             int2* __restrict__ binned,
                                             int* __restrict__ ovCnt,
                                             int2* __restrict__ ovBuf, int nbk) {
    __shared__ int2 stage[CH];                     // 32 KB
    __shared__ int hist[NBKMAX], gbase[NBKMAX], hist2[NBKMAX], sbase[NBKMAX];
    const int t = threadIdx.x;
    const int e0 = blockIdx.x * CH;
    const int len = min(CH, E - e0);
    for (int i = t; i < nbk; i += 256) { hist[i] = 0; hist2[i] = 0; }
    __syncthreads();
    for (int k = t; k < len; k += 256) {
        int s = src[e0 + k], d = dst[e0 + k];
        stage[k] = make_int2(s, d);
        atomicAdd(&hist[d >> 8], 1);
    }
    __syncthreads();
    for (int i = t; i < nbk; i += 256) {
        int c = hist[i];
        if (c) {
            int g = atomicAdd(&cursor[i], c);
            if (g + c <= BCAP) gbase[i] = g;
            else {                                  // p ~ 1e-13: spill chunk
                gbase[i] = -1;
                sbase[i] = atomicAdd(ovCnt, c);
            }
        }
    }
    __syncthreads();
    for (int k = t; k < len; k += 256) {
        int2 e = stage[k];
        int b = e.y >> 8;
        int p = atomicAdd(&hist2[b], 1);
        int g = gbase[b];
        if (g >= 0) binned[(size_t)b * BCAP + g + p] = e;
        else {
            int o = sbase[b] + p;
            if (o < OVCAP) ovBuf[o] = make_int2(e.y, e.x);
        }
    }
}

// ---------------- build: per-bucket adjacency (overlaid on binned) --------
__global__ __launch_bounds__(256) void k_build(int2* __restrict__ binned,
                                               const int* __restrict__ cursor,
                                               float* __restrict__ dinv,
                                               unsigned char* __restrict__ deg8,
                                               int* __restrict__ ovCnt,
                                               int2* __restrict__ ovBuf, int n) {
    __shared__ int2 ls[BCAP];                      // 36.9 KB
    __shared__ int lcnt[256];
    const int b = blockIdx.x, t = threadIdx.x;
    const int cnt = min(cursor[b], BCAP);
    const size_t e0 = (size_t)b * BCAP;
    for (int k = t; k < cnt; k += 256) ls[k] = binned[e0 + k];
    lcnt[t] = 0;
    __syncthreads();
    int* adjBase = (int*)binned + e0 * 2;
    for (int k = t; k < cnt; k += 256) {
        int2 e = ls[k];                            // (src, dst)
        int li = e.y & 255;
        int pos = atomicAdd(&lcnt[li], 1);
        if (pos < DSTR) adjBase[li * DSTR + pos] = e.x;
        else {
            int o = atomicAdd(ovCnt, 1);
            if (o < OVCAP) ovBuf[o] = make_int2(e.y, e.x);
        }
    }
    __syncthreads();
    int node = b * 256 + t;
    if (node < n) {
        int deg = lcnt[t];
        dinv[node] = (float)(1.0 / sqrt((double)(deg + 1)));
        deg8[node] = (unsigned char)(deg < DSTR ? deg : DSTR);
    }
}

// ---------------- GEMM: xw = x @ W^T, split-bf16 MFMA ----------------------
// Epilogue: wave-private LDS transpose (stride 132, no barrier) -> float4
// coalesced stores (128B per half-wave) instead of scalar 64B segments.
__global__ __launch_bounds__(256) void k_gemm(const float* __restrict__ x,
                                              const short* __restrict__ Whi,
                                              const short* __restrict__ Wlo,
                                              float* __restrict__ xw, int n) {
    __shared__ float trn[4 * 16 * 132];            // 33.8 KB, wave-private slices
    const int lane = threadIdx.x & 63, wv = threadIdx.x >> 6;
    const int quad = lane >> 4, m = lane & 15;
    const int rowBase = blockIdx.x * 64 + wv * 16;
    const int r = rowBase + m;
    const int rl = r < n ? r : (n - 1);
    f32x4 acc[8];
    #pragma unroll
    for (int t = 0; t < 8; t++) acc[t] = (f32x4){0.f, 0.f, 0.f, 0.f};
    #pragma unroll
    for (int s = 0; s < 4; s++) {
        const float* xp = x + (size_t)rl * 128 + s * 32 + quad * 8;
        float4 p0 = *(const float4*)xp;
        float4 p1 = *(const float4*)(xp + 4);
        float f[8] = {p0.x, p0.y, p0.z, p0.w, p1.x, p1.y, p1.z, p1.w};
        short8 ah, al;
        #pragma unroll
        for (int j = 0; j < 8; j++) {
            unsigned short hb = f2bf(f[j]);
            float hf = __uint_as_float((unsigned)hb << 16);
            ah[j] = (short)hb;
            al[j] = (short)f2bf(f[j] - hf);
        }
        #pragma unroll
        for (int t = 0; t < 8; t++) {
            short8 bh = *(const short8*)(Whi + (((s * 8 + t) * 64 + lane) << 3));
            short8 bl = *(const short8*)(Wlo + (((s * 8 + t) * 64 + lane) << 3));
            acc[t] = __builtin_amdgcn_mfma_f32_16x16x32_bf16(ah, bh, acc[t], 0, 0, 0);
            acc[t] = __builtin_amdgcn_mfma_f32_16x16x32_bf16(al, bh, acc[t], 0, 0, 0);
            acc[t] = __builtin_amdgcn_mfma_f32_16x16x32_bf16(ah, bl, acc[t], 0, 0, 0);
        }
    }
    float* tw = trn + wv * (16 * 132);
    #pragma unroll
    for (int t = 0; t < 8; t++)
        #pragma unroll
        for (int q = 0; q < 4; q++)
            tw[(quad * 4 + q) * 132 + t * 16 + m] = acc[t][q];
    // wave-private: ds_write -> ds_read ordered by lgkmcnt, no barrier needed
    #pragma unroll
    for (int i = 0; i < 8; i++) {
        int row = i * 2 + (lane >> 5);
        int c4 = lane & 31;
        float4 v = *(const float4*)(tw + row * 132 + c4 * 4);
        int grow = rowBase + row;
        if (grow < n) *(float4*)(xw + (size_t)grow * 128 + c4 * 4) = v;
    }
}

// ---------------- aggregation: 2 nodes/wave, divergent halves -------------
// lanes 0-31 = node A, 32-63 = node B; lane covers 4 cols via float4
// (32 lanes x 16B = 512B row). Each half loops over ITS degB (divergence
// masks the short half: no wasted memory traffic, unlike R4). width-32 shfl
// broadcasts (src,w) within the half. 16 rows in flight per wave.
__global__ __launch_bounds__(256) void k_agg(const float* __restrict__ xw,
                                             const unsigned char* __restrict__ deg8,
                                             const int* __restrict__ adjAll,
                                             const float* __restrict__ dinv,
                                             const float* __restrict__ conv_b,
                                             float* __restrict__ h,
                                             int base, int nEnd) {
    const int wv = threadIdx.x >> 6, lane = threadIdx.x & 63;
    const int half = lane >> 5, c4 = lane & 31;
    const int d = base + blockIdx.x * 8 + wv * 2 + half;
    if (d >= nEnd) return;
    const int degB = deg8[d];
    const float dd = dinv[d];
    const int* adjRow = adjAll + (size_t)(d >> 8) * (BCAP * 2) + (d & 255) * DSTR;
    int aj = adjRow[c4];
    bool ev = c4 < degB;
    int ajs = ev ? aj : 0;
    float dv = ev ? dinv[ajs] : 0.f;
    const float4* xw4 = (const float4*)xw;
    float4 a = xw4[(size_t)d * 32 + c4];
    float ax = dd * dd * a.x, ay = dd * dd * a.y;
    float az = dd * dd * a.z, aw = dd * dd * a.w;      // self-loop
    int j = 0;
    for (; j + 8 <= degB; j += 8) {
        int s[8];
        float w[8];
        #pragma unroll
        for (int q = 0; q < 8; q++) {
            s[q] = __shfl(ajs, j + q, 32);
            w[q] = dd * __shfl(dv, j + q, 32);
        }
        #pragma unroll
        for (int q = 0; q < 8; q++) {
            float4 v = xw4[(size_t)s[q] * 32 + c4];
            ax += w[q] * v.x; ay += w[q] * v.y;
            az += w[q] * v.z; aw += w[q] * v.w;
        }
    }
    if (j < degB) {
        int s[8];
        float w[8];
        #pragma unroll
        for (int q = 0; q < 8; q++) {
            int idx = j + q;
            bool ok = idx < degB;
            int lsrc = ok ? idx : 0;
            int sv = __shfl(ajs, lsrc, 32);
            float wq = dd * __shfl(dv, lsrc, 32);
            s[q] = ok ? sv : 0;
            w[q] = ok ? wq : 0.f;
        }
        #pragma unroll
        for (int q = 0; q < 8; q++) {
            float4 v = xw4[(size_t)s[q] * 32 + c4];
            ax += w[q] * v.x; ay += w[q] * v.y;
            az += w[q] * v.z; aw += w[q] * v.w;
        }
    }
    float4 cb = ((const float4*)conv_b)[c4];
    float4 o = make_float4(ax + cb.x, ay + cb.y, az + cb.z, aw + cb.w);
    ((float4*)h)[(size_t)d * 32 + c4] = o;
}

// ---------------- spill replay: overflow edges (expected ~5) --------------
__global__ void k_spill(const int2* __restrict__ ovBuf, const int* __restrict__ ovCnt,
                        const float* __restrict__ xw, const float* __restrict__ dinv,
                        float* __restrict__ h) {
    int m = ovCnt[0];
    if (m > OVCAP) m = OVCAP;
    int t = threadIdx.x;
    for (int i = blockIdx.x; i < m; i += gridDim.x) {
        int2 e = ovBuf[i];                       // (dst, src)
        float w = dinv[e.x] * dinv[e.y];
        if (t < 128)
            atomicAdd(&h[(size_t)e.x * 128 + t], w * xw[(size_t)e.y * 128 + t]);
    }
}

// ---------------- median 1: sampled bracket, one column per block ---------
__global__ __launch_bounds__(256) void k_sample(const float* __restrict__ h, int n,
                                                unsigned* __restrict__ Lkey,
                                                unsigned* __restrict__ Ukey) {
    __shared__ int hist[2048];
    __shared__ int wsum[4];
    const int c = blockIdx.x, t = threadIdx.x;
    for (int i = t; i < 2048; i += 256) hist[i] = 0;
    __syncthreads();
    const int ns = (n + 31) >> 5;
    for (int i = t; i < ns; i += 256) {
        float v = h[(size_t)(i << 5) * 128 + c];
        atomicAdd(&hist[ordKey(v) >> 21], 1);
    }
    __syncthreads();
    int ps = 0;
    #pragma unroll
    for (int b = 0; b < 8; b++) ps += hist[t * 8 + b];
    const int lane = t & 63, wv = t >> 6;
    int sc = ps;
    #pragma unroll
    for (int off = 1; off < 64; off <<= 1) {
        int y = __shfl_up(sc, off, 64);
        if (lane >= off) sc += y;
    }
    if (lane == 63) wsum[wv] = sc;
    __syncthreads();
    int wbase = 0;
    for (int ww = 0; ww < wv; ww++) wbase += wsum[ww];
    const int excl = wbase + sc - ps;
    const int sMid = (ns - 1) >> 1;
    const int delta = (int)(4.0f * sqrtf((float)ns)) + 1;
    int sLo = sMid - delta; if (sLo < 0) sLo = 0;
    int sHi = sMid + delta; if (sHi > ns - 1) sHi = ns - 1;
    if (sLo >= excl && sLo < excl + ps) {
        int rem = sLo - excl, b = t * 8;
        for (;; b++) { int cc = hist[b]; if (rem < cc) break; rem -= cc; }
        Lkey[c] = (unsigned)b << 21;
    }
    if (sHi >= excl && sHi < excl + ps) {
        int rem = sHi - excl, b = t * 8;
        for (;; b++) { int cc = hist[b]; if (rem < cc) break; rem -= cc; }
        Ukey[c] = (((unsigned)(b + 1)) << 21) - 1u;
    }
}

// ---------------- median 2: exact below-count + candidate collect ---------
__global__ __launch_bounds__(256) void k_collect(const float* __restrict__ h, int total4,
                                                 const unsigned* __restrict__ Lkey,
                                                 const unsigned* __restrict__ Ukey,
                                                 int* __restrict__ below,
                                                 int* __restrict__ candCnt,
                                                 float* __restrict__ cand) {
    __shared__ float buf[128 * CCAP];   // 48 KB
    __shared__ int cN[128], cB[128];
    const int t = threadIdx.x;
    for (int i = t; i < 128; i += 256) { cN[i] = 0; cB[i] = 0; }
    __syncthreads();
    const int stride = gridDim.x * blockDim.x;
    const int i0 = blockIdx.x * blockDim.x + t;
    const int jb = (i0 << 2) & 127;
    const unsigned L0 = Lkey[jb],     U0 = Ukey[jb];
    const unsigned L1 = Lkey[jb + 1], U1 = Ukey[jb + 1];
    const unsigned L2 = Lkey[jb + 2], U2 = Ukey[jb + 2];
    const unsigned L3 = Lkey[jb + 3], U3 = Ukey[jb + 3];
    int b0 = 0, b1 = 0, b2 = 0, b3 = 0;
    const float4* hv = (const float4*)h;
    for (int i = i0; i < total4; i += stride) {
        float4 v = hv[i];
        unsigned u;
        u = ordKey(v.x);
        if (u < L0) b0++;
        else if (u <= U0) { int p = atomicAdd(&cN[jb], 1); if (p < CCAP) buf[jb * CCAP + p] = v.x; }
        u = ordKey(v.y);
        if (u < L1) b1++;
        else if (u <= U1) { int p = atomicAdd(&cN[jb + 1], 1); if (p < CCAP) buf[(jb + 1) * CCAP + p] = v.y; }
        u = ordKey(v.z);
        if (u < L2) b2++;
        else if (u <= U2) { int p = atomicAdd(&cN[jb + 2], 1); if (p < CCAP) buf[(jb + 2) * CCAP + p] = v.z; }
        u = ordKey(v.w);
        if (u < L3) b3++;
        else if (u <= U3) { int p = atomicAdd(&cN[jb + 3], 1); if (p < CCAP) buf[(jb + 3) * CCAP + p] = v.w; }
    }
    if (b0) atomicAdd(&cB[jb], b0);
    if (b1) atomicAdd(&cB[jb + 1], b1);
    if (b2) atomicAdd(&cB[jb + 2], b2);
    if (b3) atomicAdd(&cB[jb + 3], b3);
    __syncthreads();
    if (t < 128) {
        if (cB[t]) atomicAdd(&below[t], cB[t]);
        int nn = cN[t] < CCAP ? cN[t] : CCAP;
        if (nn) {
            int base = atomicAdd(&candCnt[t], nn);
            for (int k = 0; k < nn && base + k < CAP; k++)
                cand[(size_t)t * CAP + base + k] = buf[t * CCAP + k];
        }
    }
}

// ---------------- median 3: 3-round radix select (11/11/10 bits) ----------
__global__ __launch_bounds__(256) void k_final(const float* __restrict__ cand,
                                               const int* __restrict__ candCnt,
                                               const int* __restrict__ below, int n,
                                               float* __restrict__ med) {
    __shared__ int hist[2048];
    __shared__ unsigned sPre;
    __shared__ int sRank;
    const int c = blockIdx.x, t = threadIdx.x;
    int cnt = candCnt[c]; if (cnt > CAP) cnt = CAP;
    const float* cp = cand + (size_t)c * CAP;
    if (t == 0) {
        int r = (n - 1) / 2 - below[c];
        if (r < 0) r = 0;
        if (r >= cnt) r = cnt - 1;
        sRank = r;
        sPre = 0u;
    }
    __syncthreads();
    #pragma unroll
    for (int round = 0; round < 3; round++) {
        const int nb = (round == 2) ? 1024 : 2048;
        for (int i = t; i < nb; i += 256) hist[i] = 0;
        __syncthreads();
        for (int i = t; i < cnt; i += 256) {
            unsigned u = ordKey(cp[i]);
            bool ok;
            int bin;
            if (round == 0)      { ok = true;                      bin = u >> 21; }
            else if (round == 1) { ok = (u >> 21) == (sPre >> 21); bin = (u >> 10) & 2047; }
            else                 { ok = (u >> 10) == (sPre >> 10); bin = u & 1023; }
            if (ok) atomicAdd(&hist[bin], 1);
        }
        __syncthreads();
        if (t < 64) {
            const int per = nb >> 6;
            int ps = 0;
            for (int b = t * per; b < t * per + per; b++) ps += hist[b];
            int sc = ps;
            #pragma unroll
            for (int off = 1; off < 64; off <<= 1) {
                int y = __shfl_up(sc, off, 64);
                if (t >= off) sc += y;
            }
            int excl = sc - ps;
            int r = sRank;
            if (excl <= r && r < sc) {
                int b = t * per, rem = r - excl;
                for (;; b++) {
                    int cc = hist[b];
                    if (rem < cc) break;
                    rem -= cc;
                }
                if (round == 0)      sPre = (unsigned)b << 21;
                else if (round == 1) sPre |= (unsigned)b << 10;
                else                 sPre |= (unsigned)b;
                sRank = rem;
            }
        }
        __syncthreads();
    }
    if (t == 0) med[c] = keyToFloat(sPre);
}

// ---------------- MLP head ----------------
__global__ void k_mlp(const float* __restrict__ med,
                      const float* __restrict__ w1, const float* __restrict__ b1,
                      const float* __restrict__ w2, const float* __restrict__ b2,
                      const float* __restrict__ w3, const float* __restrict__ b3,
                      float* __restrict__ out) {
    __shared__ float m[128], a1[64], a2[64];
    int t = threadIdx.x;
    if (t < 128) m[t] = med[t];
    __syncthreads();
    if (t < 64) {
        float acc = b1[t];
        for (int f = 0; f < 128; f++) acc += m[f] * w1[t * 128 + f];
        a1[t] = tanhf(acc);
    }
    __syncthreads();
    if (t < 64) {
        float acc = b2[t];
        for (int f = 0; f < 64; f++) acc += a1[f] * w2[t * 64 + f];
        a2[t] = tanhf(acc);
    }
    __syncthreads();
    if (t == 0) {
        float acc = b3[0];
        for (int f = 0; f < 64; f++) acc += a2[f] * w3[f];
        out[0] = acc;
    }
}

extern "C" void kernel_launch(void* const* d_in, const int* in_sizes, int n_in,
                              void* d_out, int out_size, void* d_ws, size_t ws_size,
                              hipStream_t stream) {
    const float* x      = (const float*)d_in[0];
    const int*   ei     = (const int*)d_in[1];
    const float* conv_W = (const float*)d_in[2];
    const float* conv_b = (const float*)d_in[3];
    const float* w1 = (const float*)d_in[4];
    const float* b1 = (const float*)d_in[5];
    const float* w2 = (const float*)d_in[6];
    const float* b2 = (const float*)d_in[7];
    const float* w3 = (const float*)d_in[8];
    const float* b3 = (const float*)d_in[9];

    const int N = in_sizes[0] / 128;
    const int E = in_sizes[1] / 2;
    const int* src = ei;
    const int* dst = ei + E;
    const int NBK = (N + 255) / 256;

    char* p = (char*)d_ws;
    auto alloc = [&](size_t bytes) -> char* {
        char* q = p;
        p += (bytes + 255) & ~(size_t)255;
        return q;
    };
    float* xw     = (float*)alloc((size_t)N * 128 * 4);     // dead after spill
    float* h      = (float*)alloc((size_t)N * 128 * 4);
    int2*  binned = (int2*)alloc((size_t)NBK * BCAP * 8);   // 14.4 MB; becomes
    float* cand   = (float*)binned;                         //  adj, then cand
    float* dinv   = (float*)alloc((size_t)N * 4);
    unsigned char* deg8 = (unsigned char*)alloc((size_t)N);
    int*   cursor = (int*)alloc((size_t)NBK * 4);
    short* Whi    = (short*)alloc(16384 * 2);
    short* Wlo    = (short*)alloc(16384 * 2);
    int2*  ovBuf  = (int2*)alloc((size_t)OVCAP * 8);
    int*   ovCnt  = (int*)alloc(256);
    unsigned* Lkey = (unsigned*)alloc(128 * 4);
    unsigned* Ukey = (unsigned*)alloc(128 * 4);
    int*   below   = (int*)alloc(128 * 4);
    int*   candCnt = (int*)alloc(128 * 4);
    float* med     = (float*)alloc(128 * 4);

    k_init<<<2, 256, 0, stream>>>(cursor, below, candCnt, ovCnt, conv_W, Whi, Wlo, NBK);
    k_bin<<<(E + CH - 1) / CH, 256, 0, stream>>>(src, dst, E, cursor, binned,
                                                 ovCnt, ovBuf, NBK);
    k_build<<<NBK, 256, 0, stream>>>(binned, cursor, dinv, deg8, ovCnt, ovBuf, N);
    k_gemm<<<(N + 63) / 64, 256, 0, stream>>>(x, Whi, Wlo, xw, N);
    const int N1 = (N + 1) / 2;
    k_agg<<<(N1 + 7) / 8, 256, 0, stream>>>(xw, deg8, (const int*)binned, dinv,
                                            conv_b, h, 0, N1);
    k_agg<<<(N - N1 + 7) / 8, 256, 0, stream>>>(xw, deg8, (const int*)binned, dinv,
                                                conv_b, h, N1, N);
    k_spill<<<16, 128, 0, stream>>>(ovBuf, ovCnt, xw, dinv, h);
    k_sample<<<128, 256, 0, stream>>>(h, N, Lkey, Ukey);
    k_collect<<<1024, 256, 0, stream>>>(h, N * 32, Lkey, Ukey, below, candCnt, cand);
    k_final<<<128, 256, 0, stream>>>(cand, candCnt, below, N, med);
    k_mlp<<<1, 128, 0, stream>>>(med, w1, b1, w2, b2, w3, b3, (float*)d_out);
}

// Round 8
// 389.592 us; speedup vs baseline: 1.0427x; 1.0427x over previous
//
#include <hip/hip_runtime.h>
#include <math.h>

// GraphCritic: GCNConv (sym-norm + self-loops) -> per-column lower median ->
// tanh MLP -> scalar.
// v8: k_gemm fused into k_bin (independent roles by blockIdx, union LDS; bin
//     is LDS-capped so gemm VGPRs are free). k_build = single-pass LDS
//     adjacency + coalesced dump (no edge re-stage). k_agg reverted to R6's
//     proven 1-node/wave shape (120us, 3.98 TB/s; R7 split halves = 130us).
//     k_agg is at its structural FETCH floor (8 XCD x 51MB = 408MB ~= 416
//     measured) - no further traffic reduction possible at fp32.

#define CAP    24576   // candidate capacity per column (expect ~14.3K)
#define CCAP   96      // per-block per-column LDS candidate buffer
#define DSTR   32      // adjacency slots per node
#define OVCAP  4096    // overflow edge capacity (deg>32 spill, expect ~5)
#define BCAP   4608    // edges per 256-node bucket (mean 4092, sd 64: +8 sigma)
#define NBKMAX 400
#define CH     4096    // bin chunk size

typedef __attribute__((ext_vector_type(8))) short short8;   // 8 bf16
typedef __attribute__((ext_vector_type(4))) float f32x4;

__device__ __forceinline__ unsigned ordKey(float x) {
    unsigned u = __float_as_uint(x);
    return (u & 0x80000000u) ? ~u : (u | 0x80000000u);
}
__device__ __forceinline__ float keyToFloat(unsigned k) {
    unsigned bits = (k & 0x80000000u) ? (k & 0x7FFFFFFFu) : ~k;
    return __uint_as_float(bits);
}
__device__ __forceinline__ unsigned short f2bf(float f) {   // RNE
    unsigned u = __float_as_uint(f);
    return (unsigned short)((u + 0x7FFFu + ((u >> 16) & 1u)) >> 16);
}

// ---------------- init: zero cursor/below/candCnt/ovCnt; W -> frag layout --
__global__ void k_init(int* __restrict__ cursor, int* __restrict__ below,
                       int* __restrict__ candCnt, int* __restrict__ ovCnt,
                       const float* __restrict__ W, short* __restrict__ Whi,
                       short* __restrict__ Wlo, int nbk) {
    if (blockIdx.x == 1) {
        for (int idx = threadIdx.x; idx < 16384; idx += 256) {
            int j = idx & 7, lane = (idx >> 3) & 63;
            int t = (idx >> 9) & 7, s = idx >> 12;
            int row = t * 16 + (lane & 15);
            int k = s * 32 + (lane >> 4) * 8 + j;
            float w = W[row * 128 + k];
            unsigned short hb = f2bf(w);
            float hf = __uint_as_float((unsigned)hb << 16);
            Whi[idx] = (short)hb;
            Wlo[idx] = (short)f2bf(w - hf);
        }
        return;
    }
    int t = threadIdx.x;
    for (int i = t; i < nbk; i += 256) cursor[i] = 0;
    if (t < 128) { below[t] = 0; candCnt[t] = 0; }
    if (t == 0) ovCnt[0] = 0;
}

// ---------------- fused: split-bf16 MFMA GEMM + bucket binning -------------
// Blocks [0,GB): xw = x @ W^T. Blocks [GB,GB+BINB): chunked LDS binning.
// LDS is a union: gemm uses 33.8KB transpose slab; bin uses 32KB stage+6.4KB
// hists (39.2KB total -> 4 blocks/CU either way).
__global__ __launch_bounds__(256) void k_binGemm(
        const float* __restrict__ x, const short* __restrict__ Whi,
        const short* __restrict__ Wlo, float* __restrict__ xw, int n, int GB,
        const int* __restrict__ src, const int* __restrict__ dst, int E,
        int* __restrict__ cursor, int2* __restrict__ binned,
        int* __restrict__ ovCnt, int2* __restrict__ ovBuf, int nbk) {
    __shared__ char smem[39168];
    const int t = threadIdx.x;
    if ((int)blockIdx.x < GB) {
        // ---- GEMM role ----
        float* trn = (float*)smem;                 // 4 waves x 16 x 132 floats
        const int lane = t & 63, wv = t >> 6;
        const int quad = lane >> 4, m = lane & 15;
        const int rowBase = blockIdx.x * 64 + wv * 16;
        const int r = rowBase + m;
        const int rl = r < n ? r : (n - 1);
        f32x4 acc[8];
        #pragma unroll
        for (int q = 0; q < 8; q++) acc[q] = (f32x4){0.f, 0.f, 0.f, 0.f};
        #pragma unroll
        for (int s = 0; s < 4; s++) {
            const float* xp = x + (size_t)rl * 128 + s * 32 + quad * 8;
            float4 p0 = *(const float4*)xp;
            float4 p1 = *(const float4*)(xp + 4);
            float f[8] = {p0.x, p0.y, p0.z, p0.w, p1.x, p1.y, p1.z, p1.w};
            short8 ah, al;
            #pragma unroll
            for (int j = 0; j < 8; j++) {
                unsigned short hb = f2bf(f[j]);
                float hf = __uint_as_float((unsigned)hb << 16);
                ah[j] = (short)hb;
                al[j] = (short)f2bf(f[j] - hf);
            }
            #pragma unroll
            for (int q = 0; q < 8; q++) {
                short8 bh = *(const short8*)(Whi + (((s * 8 + q) * 64 + lane) << 3));
                short8 bl = *(const short8*)(Wlo + (((s * 8 + q) * 64 + lane) << 3));
                acc[q] = __builtin_amdgcn_mfma_f32_16x16x32_bf16(ah, bh, acc[q], 0, 0, 0);
                acc[q] = __builtin_amdgcn_mfma_f32_16x16x32_bf16(al, bh, acc[q], 0, 0, 0);
                acc[q] = __builtin_amdgcn_mfma_f32_16x16x32_bf16(ah, bl, acc[q], 0, 0, 0);
            }
        }
        float* tw = trn + wv * (16 * 132);
        #pragma unroll
        for (int q = 0; q < 8; q++)
            #pragma unroll
            for (int e = 0; e < 4; e++)
                tw[(quad * 4 + e) * 132 + q * 16 + m] = acc[q][e];
        // wave-private ds_write->ds_read ordered by lgkmcnt: no barrier
        #pragma unroll
        for (int i = 0; i < 8; i++) {
            int row = i * 2 + (lane >> 5);
            int c4 = lane & 31;
            float4 v = *(const float4*)(tw + row * 132 + c4 * 4);
            int grow = rowBase + row;
            if (grow < n) *(float4*)(xw + (size_t)grow * 128 + c4 * 4) = v;
        }
    } else {
        // ---- BIN role ----
        int2* stage = (int2*)smem;                 // 32 KB
        int* hist  = (int*)(smem + 32768);
        int* gbase = hist + NBKMAX;
        int* hist2 = gbase + NBKMAX;
        int* sbase = hist2 + NBKMAX;
        const int e0 = ((int)blockIdx.x - GB) * CH;
        const int len = min(CH, E - e0);
        for (int i = t; i < nbk; i += 256) { hist[i] = 0; hist2[i] = 0; }
        __syncthreads();
        for (int k = t; k < len; k += 256) {
            int s = src[e0 + k], d = dst[e0 + k];
            stage[k] = make_int2(s, d);
            atomicAdd(&hist[d >> 8], 1);
        }
        __syncthreads();
        for (int i = t; i < nbk; i += 256) {
            int c = hist[i];
            if (c) {
                int g = atomicAdd(&cursor[i], c);
                if (g + c <= BCAP) gbase[i] = g;
                else {                              // p ~ 1e-13: spill chunk
                    gbase[i] = -1;
                    sbase[i] = atomicAdd(ovCnt, c);
                }
            }
        }
        __syncthreads();
        for (int k = t; k < len; k += 256) {
            int2 e = stage[k];
            int b = e.y >> 8;
            int p = atomicAdd(&hist2[b], 1);
            int g = gbase[b];
            if (g >= 0) binned[(size_t)b * BCAP + g + p] = e;
            else {
                int o = sbase[b] + p;
                if (o < OVCAP) ovBuf[o] = make_int2(e.y, e.x);
            }
        }
    }
}

// ---------------- build: single-pass LDS adjacency + coalesced dump -------
// Block b: scatter its bucket's edges into a 32KB LDS adjacency (LDS atomics),
// then int4-dump over the bucket's own binned region. Garbage slots beyond
// deg are never read (k_agg masks by deg8).
__global__ __launch_bounds__(256) void k_build(int2* __restrict__ binned,
                                               const int* __restrict__ cursor,
                                               float* __restrict__ dinv,
                                               unsigned char* __restrict__ deg8,
                                               int* __restrict__ ovCnt,
                                               int2* __restrict__ ovBuf, int n) {
    __shared__ int ladj[256 * DSTR];               // 32 KB
    __shared__ int lcnt[256];
    const int b = blockIdx.x, t = threadIdx.x;
    const int cnt = min(cursor[b], BCAP);
    const size_t e0 = (size_t)b * BCAP;
    lcnt[t] = 0;
    __syncthreads();
    for (int k = t; k < cnt; k += 256) {
        int2 e = binned[e0 + k];                   // (src, dst)
        int li = e.y & 255;
        int pos = atomicAdd(&lcnt[li], 1);
        if (pos < DSTR) ladj[li * DSTR + pos] = e.x;
        else {
            int o = atomicAdd(ovCnt, 1);
            if (o < OVCAP) ovBuf[o] = make_int2(e.y, e.x);
        }
    }
    __syncthreads();
    int4* adjOut = (int4*)((int*)binned + e0 * 2);
    const int4* lsrc4 = (const int4*)ladj;
    for (int i = t; i < 2048; i += 256) adjOut[i] = lsrc4[i];
    int node = b * 256 + t;
    if (node < n) {
        int deg = lcnt[t];
        dinv[node] = (float)(1.0 / sqrt((double)(deg + 1)));
        deg8[node] = (unsigned char)(deg < DSTR ? deg : DSTR);
    }
}

// ---------------- aggregation: 1 node/wave, shfl-broadcast (R6 form) ------
__global__ __launch_bounds__(256) void k_agg(const float* __restrict__ xw,
                                             const unsigned char* __restrict__ deg8,
                                             const int* __restrict__ adjAll,
                                             const float* __restrict__ dinv,
                                             const float* __restrict__ conv_b,
                                             float* __restrict__ h, int n) {
    const int d = blockIdx.x * 4 + (threadIdx.x >> 6);
    if (d >= n) return;
    const int lane = threadIdx.x & 63;
    const int l32 = lane & 31;
    const int degB = deg8[d];
    const float dd = dinv[d];
    const int* adjRow = adjAll + (size_t)(d >> 8) * (BCAP * 2) + (d & 255) * DSTR;
    int aj = adjRow[l32];
    bool ev = (lane < 32) && (l32 < degB);
    int ajs = ev ? aj : 0;
    float dv = ev ? dinv[ajs] : 0.f;
    const float2* xwv = (const float2*)xw;
    float2 a = xwv[(size_t)d * 64 + lane];
    float ax = dd * dd * a.x, ay = dd * dd * a.y;   // self-loop
    int j = 0;
    for (; j + 8 <= degB; j += 8) {
        int s[8];
        float w[8];
        #pragma unroll
        for (int q = 0; q < 8; q++) {
            s[q] = __shfl(ajs, j + q, 64);
            w[q] = dd * __shfl(dv, j + q, 64);
        }
        #pragma unroll
        for (int q = 0; q < 8; q++) {
            float2 v = xwv[(size_t)s[q] * 64 + lane];
            ax += w[q] * v.x;
            ay += w[q] * v.y;
        }
    }
    if (j < degB) {
        int s[8];
        float w[8];
        #pragma unroll
        for (int q = 0; q < 8; q++) {
            int idx = j + q;
            bool ok = idx < degB;
            int lsrc = ok ? idx : 0;
            int sv = __shfl(ajs, lsrc, 64);
            float wv = dd * __shfl(dv, lsrc, 64);
            s[q] = ok ? sv : 0;
            w[q] = ok ? wv : 0.f;
        }
        #pragma unroll
        for (int q = 0; q < 8; q++) {
            float2 v = xwv[(size_t)s[q] * 64 + lane];
            ax += w[q] * v.x;
            ay += w[q] * v.y;
        }
    }
    float2 cb = ((const float2*)conv_b)[lane];
    float2 o;
    o.x = ax + cb.x;
    o.y = ay + cb.y;
    ((float2*)h)[(size_t)d * 64 + lane] = o;
}

// ---------------- spill replay: overflow edges (expected ~5) --------------
__global__ void k_spill(const int2* __restrict__ ovBuf, const int* __restrict__ ovCnt,
                        const float* __restrict__ xw, const float* __restrict__ dinv,
                        float* __restrict__ h) {
    int m = ovCnt[0];
    if (m > OVCAP) m = OVCAP;
    int t = threadIdx.x;
    for (int i = blockIdx.x; i < m; i += gridDim.x) {
        int2 e = ovBuf[i];                       // (dst, src)
        float w = dinv[e.x] * dinv[e.y];
        if (t < 128)
            atomicAdd(&h[(size_t)e.x * 128 + t], w * xw[(size_t)e.y * 128 + t]);
    }
}

// ---------------- median 1: sampled bracket, one column per block ---------
__global__ __launch_bounds__(256) void k_sample(const float* __restrict__ h, int n,
                                                unsigned* __restrict__ Lkey,
                                                unsigned* __restrict__ Ukey) {
    __shared__ int hist[2048];
    __shared__ int wsum[4];
    const int c = blockIdx.x, t = threadIdx.x;
    for (int i = t; i < 2048; i += 256) hist[i] = 0;
    __syncthreads();
    const int ns = (n + 31) >> 5;
    for (int i = t; i < ns; i += 256) {
        float v = h[(size_t)(i << 5) * 128 + c];
        atomicAdd(&hist[ordKey(v) >> 21], 1);
    }
    __syncthreads();
    int ps = 0;
    #pragma unroll
    for (int b = 0; b < 8; b++) ps += hist[t * 8 + b];
    const int lane = t & 63, wv = t >> 6;
    int sc = ps;
    #pragma unroll
    for (int off = 1; off < 64; off <<= 1) {
        int y = __shfl_up(sc, off, 64);
        if (lane >= off) sc += y;
    }
    if (lane == 63) wsum[wv] = sc;
    __syncthreads();
    int wbase = 0;
    for (int ww = 0; ww < wv; ww++) wbase += wsum[ww];
    const int excl = wbase + sc - ps;
    const int sMid = (ns - 1) >> 1;
    const int delta = (int)(4.0f * sqrtf((float)ns)) + 1;
    int sLo = sMid - delta; if (sLo < 0) sLo = 0;
    int sHi = sMid + delta; if (sHi > ns - 1) sHi = ns - 1;
    if (sLo >= excl && sLo < excl + ps) {
        int rem = sLo - excl, b = t * 8;
        for (;; b++) { int cc = hist[b]; if (rem < cc) break; rem -= cc; }
        Lkey[c] = (unsigned)b << 21;
    }
    if (sHi >= excl && sHi < excl + ps) {
        int rem = sHi - excl, b = t * 8;
        for (;; b++) { int cc = hist[b]; if (rem < cc) break; rem -= cc; }
        Ukey[c] = (((unsigned)(b + 1)) << 21) - 1u;
    }
}

// ---------------- median 2: exact below-count + candidate collect ---------
__global__ __launch_bounds__(256) void k_collect(const float* __restrict__ h, int total4,
                                                 const unsigned* __restrict__ Lkey,
                                                 const unsigned* __restrict__ Ukey,
                                                 int* __restrict__ below,
                                                 int* __restrict__ candCnt,
                                                 float* __restrict__ cand) {
    __shared__ float buf[128 * CCAP];   // 48 KB
    __shared__ int cN[128], cB[128];
    const int t = threadIdx.x;
    for (int i = t; i < 128; i += 256) { cN[i] = 0; cB[i] = 0; }
    __syncthreads();
    const int stride = gridDim.x * blockDim.x;
    const int i0 = blockIdx.x * blockDim.x + t;
    const int jb = (i0 << 2) & 127;
    const unsigned L0 = Lkey[jb],     U0 = Ukey[jb];
    const unsigned L1 = Lkey[jb + 1], U1 = Ukey[jb + 1];
    const unsigned L2 = Lkey[jb + 2], U2 = Ukey[jb + 2];
    const unsigned L3 = Lkey[jb + 3], U3 = Ukey[jb + 3];
    int b0 = 0, b1 = 0, b2 = 0, b3 = 0;
    const float4* hv = (const float4*)h;
    for (int i = i0; i < total4; i += stride) {
        float4 v = hv[i];
        unsigned u;
        u = ordKey(v.x);
        if (u < L0) b0++;
        else if (u <= U0) { int p = atomicAdd(&cN[jb], 1); if (p < CCAP) buf[jb * CCAP + p] = v.x; }
        u = ordKey(v.y);
        if (u < L1) b1++;
        else if (u <= U1) { int p = atomicAdd(&cN[jb + 1], 1); if (p < CCAP) buf[(jb + 1) * CCAP + p] = v.y; }
        u = ordKey(v.z);
        if (u < L2) b2++;
        else if (u <= U2) { int p = atomicAdd(&cN[jb + 2], 1); if (p < CCAP) buf[(jb + 2) * CCAP + p] = v.z; }
        u = ordKey(v.w);
        if (u < L3) b3++;
        else if (u <= U3) { int p = atomicAdd(&cN[jb + 3], 1); if (p < CCAP) buf[(jb + 3) * CCAP + p] = v.w; }
    }
    if (b0) atomicAdd(&cB[jb], b0);
    if (b1) atomicAdd(&cB[jb + 1], b1);
    if (b2) atomicAdd(&cB[jb + 2], b2);
    if (b3) atomicAdd(&cB[jb + 3], b3);
    __syncthreads();
    if (t < 128) {
        if (cB[t]) atomicAdd(&below[t], cB[t]);
        int nn = cN[t] < CCAP ? cN[t] : CCAP;
        if (nn) {
            int base = atomicAdd(&candCnt[t], nn);
            for (int k = 0; k < nn && base + k < CAP; k++)
                cand[(size_t)t * CAP + base + k] = buf[t * CCAP + k];
        }
    }
}

// ---------------- median 3: 3-round radix select (11/11/10 bits) ----------
__global__ __launch_bounds__(256) void k_final(const float* __restrict__ cand,
                                               const int* __restrict__ candCnt,
                                               const int* __restrict__ below, int n,
                                               float* __restrict__ med) {
    __shared__ int hist[2048];
    __shared__ unsigned sPre;
    __shared__ int sRank;
    const int c = blockIdx.x, t = threadIdx.x;
    int cnt = candCnt[c]; if (cnt > CAP) cnt = CAP;
    const float* cp = cand + (size_t)c * CAP;
    if (t == 0) {
        int r = (n - 1) / 2 - below[c];
        if (r < 0) r = 0;
        if (r >= cnt) r = cnt - 1;
        sRank = r;
        sPre = 0u;
    }
    __syncthreads();
    #pragma unroll
    for (int round = 0; round < 3; round++) {
        const int nb = (round == 2) ? 1024 : 2048;
        for (int i = t; i < nb; i += 256) hist[i] = 0;
        __syncthreads();
        for (int i = t; i < cnt; i += 256) {
            unsigned u = ordKey(cp[i]);
            bool ok;
            int bin;
            if (round == 0)      { ok = true;                      bin = u >> 21; }
            else if (round == 1) { ok = (u >> 21) == (sPre >> 21); bin = (u >> 10) & 2047; }
            else                 { ok = (u >> 10) == (sPre >> 10); bin = u & 1023; }
            if (ok) atomicAdd(&hist[bin], 1);
        }
        __syncthreads();
        if (t < 64) {
            const int per = nb >> 6;
            int ps = 0;
            for (int b = t * per; b < t * per + per; b++) ps += hist[b];
            int sc = ps;
            #pragma unroll
            for (int off = 1; off < 64; off <<= 1) {
                int y = __shfl_up(sc, off, 64);
                if (t >= off) sc += y;
            }
            int excl = sc - ps;
            int r = sRank;
            if (excl <= r && r < sc) {
                int b = t * per, rem = r - excl;
                for (;; b++) {
                    int cc = hist[b];
                    if (rem < cc) break;
                    rem -= cc;
                }
                if (round == 0)      sPre = (unsigned)b << 21;
                else if (round == 1) sPre |= (unsigned)b << 10;
                else                 sPre |= (unsigned)b;
                sRank = rem;
            }
        }
        __syncthreads();
    }
    if (t == 0) med[c] = keyToFloat(sPre);
}

// ---------------- MLP head ----------------
__global__ void k_mlp(const float* __restrict__ med,
                      const float* __restrict__ w1, const float* __restrict__ b1,
                      const float* __restrict__ w2, const float* __restrict__ b2,
                      const float* __restrict__ w3, const float* __restrict__ b3,
                      float* __restrict__ out) {
    __shared__ float m[128], a1[64], a2[64];
    int t = threadIdx.x;
    if (t < 128) m[t] = med[t];
    __syncthreads();
    if (t < 64) {
        float acc = b1[t];
        for (int f = 0; f < 128; f++) acc += m[f] * w1[t * 128 + f];
        a1[t] = tanhf(acc);
    }
    __syncthreads();
    if (t < 64) {
        float acc = b2[t];
        for (int f = 0; f < 64; f++) acc += a1[f] * w2[t * 64 + f];
        a2[t] = tanhf(acc);
    }
    __syncthreads();
    if (t == 0) {
        float acc = b3[0];
        for (int f = 0; f < 64; f++) acc += a2[f] * w3[f];
        out[0] = acc;
    }
}

extern "C" void kernel_launch(void* const* d_in, const int* in_sizes, int n_in,
                              void* d_out, int out_size, void* d_ws, size_t ws_size,
                              hipStream_t stream) {
    const float* x      = (const float*)d_in[0];
    const int*   ei     = (const int*)d_in[1];
    const float* conv_W = (const float*)d_in[2];
    const float* conv_b = (const float*)d_in[3];
    const float* w1 = (const float*)d_in[4];
    const float* b1 = (const float*)d_in[5];
    const float* w2 = (const float*)d_in[6];
    const float* b2 = (const float*)d_in[7];
    const float* w3 = (const float*)d_in[8];
    const float* b3 = (const float*)d_in[9];

    const int N = in_sizes[0] / 128;
    const int E = in_sizes[1] / 2;
    const int* src = ei;
    const int* dst = ei + E;
    const int NBK = (N + 255) / 256;

    char* p = (char*)d_ws;
    auto alloc = [&](size_t bytes) -> char* {
        char* q = p;
        p += (bytes + 255) & ~(size_t)255;
        return q;
    };
    float* xw     = (float*)alloc((size_t)N * 128 * 4);     // dead after spill
    float* h      = (float*)alloc((size_t)N * 128 * 4);
    int2*  binned = (int2*)alloc((size_t)NBK * BCAP * 8);   // 14.4 MB; becomes
    float* cand   = (float*)binned;                         //  adj, then cand
    float* dinv   = (float*)alloc((size_t)N * 4);
    unsigned char* deg8 = (unsigned char*)alloc((size_t)N);
    int*   cursor = (int*)alloc((size_t)NBK * 4);
    short* Whi    = (short*)alloc(16384 * 2);
    short* Wlo    = (short*)alloc(16384 * 2);
    int2*  ovBuf  = (int2*)alloc((size_t)OVCAP * 8);
    int*   ovCnt  = (int*)alloc(256);
    unsigned* Lkey = (unsigned*)alloc(128 * 4);
    unsigned* Ukey = (unsigned*)alloc(128 * 4);
    int*   below   = (int*)alloc(128 * 4);
    int*   candCnt = (int*)alloc(128 * 4);
    float* med     = (float*)alloc(128 * 4);

    const int GB   = (N + 63) / 64;          // gemm blocks
    const int BINB = (E + CH - 1) / CH;      // bin blocks

    k_init<<<2, 256, 0, stream>>>(cursor, below, candCnt, ovCnt, conv_W, Whi, Wlo, NBK);
    k_binGemm<<<GB + BINB, 256, 0, stream>>>(x, Whi, Wlo, xw, N, GB,
                                             src, dst, E, cursor, binned,
                                             ovCnt, ovBuf, NBK);
    k_build<<<NBK, 256, 0, stream>>>(binned, cursor, dinv, deg8, ovCnt, ovBuf, N);
    k_agg<<<(N + 3) / 4, 256, 0, stream>>>(xw, deg8, (const int*)binned, dinv,
                                           conv_b, h, N);
    k_spill<<<16, 128, 0, stream>>>(ovBuf, ovCnt, xw, dinv, h);
    k_sample<<<128, 256, 0, stream>>>(h, N, Lkey, Ukey);
    k_collect<<<1024, 256, 0, stream>>>(h, N * 32, Lkey, Ukey, below, candCnt, cand);
    k_final<<<128, 256, 0, stream>>>(cand, candCnt, below, N, med);
    k_mlp<<<1, 128, 0, stream>>>(med, w1, b1, w2, b2, w3, b3, (float*)d_out);
}